// Round 11
// baseline (1292.675 us; speedup 1.0000x reference)
//
#include <hip/hip_runtime.h>
#include <hip/hip_fp16.h>

typedef _Float16 f16;
typedef _Float16 f16x8 __attribute__((ext_vector_type(8)));
typedef _Float16 f16x4 __attribute__((ext_vector_type(4)));
typedef float    f32x4 __attribute__((ext_vector_type(4)));

#define DECAY   0.99f
#define MARGIN  0.3f     // stage-1 hh f16 pairwise error sigma ~0.026; 0.3 ~ 11 sigma (R3-validated)
#define MARGIN2 2e-3f    // stage-2 3-pass error sigma ~1.5e-4; 2e-3 ~ 13 sigma
#define MAXA    4096     // stage-2 row capacity; overflow falls through to exact f64 scan

#define BM    128   // stage-1 rows per block
#define CT    128   // codes per tile
#define BD    64    // contraction elems per stage step
#define NSPAN 2     // stage-1 K-split (R8-validated best: 512 blocks, 2/CU)
#define NSPAN2 32   // stage-2 K-split (256 cols per block)

// async global->LDS, 16B per lane, wave-uniform LDS base
__device__ __forceinline__ void gl_lds16(const void* g, void* l) {
  __builtin_amdgcn_global_load_lds(
      (const __attribute__((address_space(1))) unsigned int*)g,
      (__attribute__((address_space(3))) unsigned int*)l, 16, 0, 0);
}

// ---- prep: cb = codebook/counts, f16 hi+lo, exact f32 ||cb||^2; zero hist/counters ----
__global__ void prep_cb(const float* __restrict__ codebook, const float* __restrict__ counts,
                        f16* __restrict__ cHi, f16* __restrict__ cLo, float* __restrict__ cnorm,
                        unsigned* __restrict__ hist, unsigned* __restrict__ cnts, int D) {
  const int k = blockIdx.x;
  const int tid = threadIdx.x;  // 128 threads, D==512 -> 1 float4 each
  const float cnt = counts[k];
  float4 v = ((const float4*)(codebook + (size_t)k * D))[tid];
  float c0 = v.x / cnt, c1 = v.y / cnt, c2 = v.z / cnt, c3 = v.w / cnt;
  f16 h0 = (f16)c0, h1 = (f16)c1, h2 = (f16)c2, h3 = (f16)c3;
  f16x4 h = {h0, h1, h2, h3};
  f16x4 l = {(f16)(c0 - (float)h0), (f16)(c1 - (float)h1),
             (f16)(c2 - (float)h2), (f16)(c3 - (float)h3)};
  *(f16x4*)(cHi + (size_t)k * D + tid * 4) = h;
  *(f16x4*)(cLo + (size_t)k * D + tid * 4) = l;
  float s = c0*c0 + c1*c1 + c2*c2 + c3*c3;
  #pragma unroll
  for (int m = 1; m < 64; m <<= 1) s += __shfl_xor(s, m);
  __shared__ float red[2];
  if ((tid & 63) == 0) red[tid >> 6] = s;
  __syncthreads();
  if (tid == 0) {
    cnorm[k] = red[0] + red[1];
    hist[k] = 0u;
    if (k == 0) { cnts[0] = 0u; cnts[64] = 0u; }
  }
}

// ---- prep: target f16 hi ----
__global__ void prep_t(const float4* __restrict__ t4, f16x4* __restrict__ hi4, long total4) {
  for (long i = blockIdx.x * (long)blockDim.x + threadIdx.x; i < total4;
       i += (long)gridDim.x * blockDim.x) {
    float4 v = t4[i];
    f16x4 h = {(f16)v.x, (f16)v.y, (f16)v.z, (f16)v.w};
    hi4[i] = h;
  }
}

// ---- stage 1: lean 128x128 single-pass hh f16 MFMA, high-occupancy 2-barrier loop,
//      per-lane running top-2 across tiles, one 16-lane reduce at the end (R8 config). ----
__global__ __launch_bounds__(256, 4)
void argmin_pass(const f16* __restrict__ tHi, const f16* __restrict__ cHi,
                 const float* __restrict__ cnorm, float4* __restrict__ partials,
                 int D, int CSPAN) {
  __shared__ __align__(16) unsigned char smem[2 * BM * BD * 2];  // A 16K | B 16K
  unsigned char* ldsA = smem;
  unsigned char* ldsB = smem + BM * BD * 2;

  const int tid = threadIdx.x;
  const int w = tid >> 6, lane = tid & 63;
  const int rowBase = blockIdx.x * BM;
  const int span = blockIdx.y;
  const int colBase = span * CSPAN;

  // staging map: slot s=(i*4+w)*64+lane -> row r=s>>3, 16B-chunk c=s&7; fetch chunk c^(r&7)
  // (global-source XOR swizzle; LDS linear; fragment reads apply the same XOR)
  int rloc[4], exel[4], ldsOff[4];
  #pragma unroll
  for (int i = 0; i < 4; ++i) {
    int s = (i * 4 + w) * 64 + lane;
    int r = s >> 3, c = s & 7;
    rloc[i] = r;
    exel[i] = (c ^ (r & 7)) * 8;
    ldsOff[i] = (i * 4 + w) * 1024;
  }
  size_t aBase[4];
  #pragma unroll
  for (int i = 0; i < 4; ++i) aBase[i] = (size_t)(rowBase + rloc[i]) * D + exel[i];

  // per-lane running top-2 (per m,j): candidates are this lane's 16-col slot across all tiles
  float rm1[8], rm2[8];
  unsigned ra1[8];
  #pragma unroll
  for (int i = 0; i < 8; ++i) { rm1[i] = __builtin_inff(); rm2[i] = __builtin_inff(); ra1[i] = 0u; }

  const int NT = CSPAN / CT;   // 32
  #pragma unroll 1
  for (int tile = 0; tile < NT; ++tile) {
    const int c0 = colBase + tile * CT;
    size_t bOff[4];
    #pragma unroll
    for (int i = 0; i < 4; ++i) bOff[i] = (size_t)(c0 + rloc[i]) * D + exel[i];

    f32x4 acc[2][8];
    #pragma unroll
    for (int m = 0; m < 2; ++m)
      #pragma unroll
      for (int n = 0; n < 8; ++n) { f32x4 z = {0.f, 0.f, 0.f, 0.f}; acc[m][n] = z; }

    #pragma unroll 1
    for (int ds = 0; ds < 8; ++ds) {
      const int d0 = ds * BD;
      __syncthreads();
      #pragma unroll
      for (int i = 0; i < 4; ++i) gl_lds16(tHi + aBase[i] + d0, ldsA + ldsOff[i]);
      #pragma unroll
      for (int i = 0; i < 4; ++i) gl_lds16(cHi + bOff[i] + d0, ldsB + ldsOff[i]);
      __syncthreads();
      #pragma unroll
      for (int ks = 0; ks < 2; ++ks) {
        const int chunk = ks * 4 + (lane >> 4);
        f16x8 af[2];
        #pragma unroll
        for (int m = 0; m < 2; ++m) {
          int r = w * 32 + m * 16 + (lane & 15);
          af[m] = *(const f16x8*)(ldsA + r * 128 + ((chunk ^ (r & 7)) * 16));
        }
        f16x8 bfr[8];
        #pragma unroll
        for (int n = 0; n < 8; ++n) {
          int r = n * 16 + (lane & 15);
          bfr[n] = *(const f16x8*)(ldsB + r * 128 + ((chunk ^ (r & 7)) * 16));
        }
        #pragma unroll
        for (int m = 0; m < 2; ++m)
          #pragma unroll
          for (int n = 0; n < 8; ++n)
            acc[m][n] = __builtin_amdgcn_mfma_f32_16x16x32_f16(af[m], bfr[n], acc[m][n], 0, 0, 0);
      }
    }

    // per-lane merge only (no cross-lane work inside the tile loop)
    float cn[8];
    #pragma unroll
    for (int n = 0; n < 8; ++n) cn[n] = cnorm[c0 + n * 16 + (lane & 15)];
    #pragma unroll
    for (int m = 0; m < 2; ++m) {
      #pragma unroll
      for (int j = 0; j < 4; ++j) {
        const int idx = m * 4 + j;
        float v1 = rm1[idx], v2 = rm2[idx];
        unsigned b1 = ra1[idx];
        #pragma unroll
        for (int n = 0; n < 8; ++n) {
          float v = fmaf(-2.0f, acc[m][n][j], cn[n]);
          unsigned c = (unsigned)(c0 + n * 16 + (lane & 15));
          if (v < v1) { v2 = v1; v1 = v; b1 = c; }   // strict <, ascending cols => first index
          else if (v < v2) { v2 = v; }
        }
        rm1[idx] = v1; rm2[idx] = v2; ra1[idx] = b1;
      }
    }
  }

  // final: 16-lane-group top-2 reduce, then write per-row partials
  const int g = lane >> 4;
  #pragma unroll
  for (int m = 0; m < 2; ++m) {
    #pragma unroll
    for (int j = 0; j < 4; ++j) {
      const int idx = m * 4 + j;
      float m1 = rm1[idx], m2 = rm2[idx];
      unsigned a1 = ra1[idx];
      #pragma unroll
      for (int msk = 1; msk < 16; msk <<= 1) {
        float o1 = __shfl_xor(m1, msk);
        unsigned oa = (unsigned)__shfl_xor((int)a1, msk);
        float o2 = __shfl_xor(m2, msk);
        bool bet = (o1 < m1) || (o1 == m1 && oa < a1);
        float nm2 = bet ? fminf(m1, o2) : fminf(m2, o1);
        if (bet) { m1 = o1; a1 = oa; }
        m2 = nm2;
      }
      if ((lane & 15) == 0) {
        int r = rowBase + w * 32 + m * 16 + g * 4 + j;
        float4 p;
        p.x = m1;
        p.y = __uint_as_float(a1);
        p.z = m2;
        p.w = 0.f;
        partials[(size_t)r * NSPAN + span] = p;
      }
    }
  }
}

// ---- merge stage-1 spans -> labels + inline histogram; flag ambiguous rows ----
__global__ void reduce_labels(const float4* __restrict__ partials, int* __restrict__ labels,
                              unsigned* __restrict__ hist,
                              unsigned* __restrict__ cnts, unsigned* __restrict__ list1,
                              unsigned* __restrict__ list2, int N) {
  int r = blockIdx.x * blockDim.x + threadIdx.x;
  if (r >= N) return;
  float m1 = __builtin_inff(), m2 = __builtin_inff();
  unsigned a1 = 0u;
  #pragma unroll
  for (int s = 0; s < NSPAN; ++s) {
    float4 p = partials[(size_t)r * NSPAN + s];
    float o1 = p.x;
    unsigned oa = __float_as_uint(p.y);
    float o2 = p.z;
    bool bet = (o1 < m1) || (o1 == m1 && oa < a1);
    float nm2 = bet ? fminf(m1, o2) : fminf(m2, o1);
    if (bet) { m1 = o1; a1 = oa; }
    m2 = nm2;
  }
  labels[r] = (int)a1;
  atomicAdd(&hist[a1], 1u);   // stage-1 histogram; refine stages patch deltas
  if (m2 - m1 < MARGIN) {
    unsigned idx = atomicAdd(&cnts[0], 1u);
    if (idx < MAXA) list1[idx] = (unsigned)r;
    else { unsigned i2 = atomicAdd(&cnts[64], 1u); list2[i2] = (unsigned)r; }
  }
}

// ---- gather flagged rows' targets as f16 hi/lo splits ----
__global__ void gather_k(const float4* __restrict__ t4, const unsigned* __restrict__ cnts,
                         const unsigned* __restrict__ list1, f16x4* __restrict__ gHi4,
                         f16x4* __restrict__ gLo4) {
  unsigned i = blockIdx.x * blockDim.x + threadIdx.x;  // one float4 unit
  unsigned a = i >> 7, j = i & 127;
  unsigned cntA = cnts[0] < MAXA ? cnts[0] : MAXA;
  if (a >= cntA) return;
  unsigned r = list1[a];
  float4 v = t4[(size_t)r * 128 + j];
  f16 h0 = (f16)v.x, h1 = (f16)v.y, h2 = (f16)v.z, h3 = (f16)v.w;
  f16x4 h = {h0, h1, h2, h3};
  f16x4 l = {(f16)(v.x - (float)h0), (f16)(v.y - (float)h1),
             (f16)(v.z - (float)h2), (f16)(v.w - (float)h3)};
  gHi4[(size_t)a * 128 + j] = h;
  gLo4[(size_t)a * 128 + j] = l;
}

// ---- stage 2: 3-pass (hh, h*lo, lo*h) MFMA re-score of flagged rows, full K ----
__global__ __launch_bounds__(256, 2)
void refine_mfma(const f16* __restrict__ gHi, const f16* __restrict__ gLo,
                 const f16* __restrict__ cHi, const f16* __restrict__ cLo,
                 const float* __restrict__ cnorm, const unsigned* __restrict__ cnts,
                 float4* __restrict__ partials2, int D) {
  __shared__ __align__(16) unsigned char smem[2 * 128 * 64 * 2];  // A 16K | B 16K
  unsigned char* ldsA = smem;
  unsigned char* ldsB = smem + 128 * 64 * 2;

  const unsigned cntA = cnts[0] < MAXA ? cnts[0] : MAXA;
  const int rowBase = blockIdx.x * 128;
  if ((unsigned)rowBase >= cntA) return;
  const int colBase = blockIdx.y * 256;  // CSPAN2 = 256, NT = 2

  const int tid = threadIdx.x;
  const int w = tid >> 6, lane = tid & 63;

  int rloc[4], exel[4], ldsOff[4];
  #pragma unroll
  for (int i = 0; i < 4; ++i) {
    int s = (i * 4 + w) * 64 + lane;
    int r = s >> 3, c = s & 7;
    rloc[i] = r;
    exel[i] = (c ^ (r & 7)) * 8;
    ldsOff[i] = (i * 4 + w) * 1024;
  }
  size_t aBase[4];
  #pragma unroll
  for (int i = 0; i < 4; ++i) aBase[i] = (size_t)(rowBase + rloc[i]) * D + exel[i];

  float rm1[8], rm2[8];
  unsigned ra1[8];
  #pragma unroll
  for (int i = 0; i < 8; ++i) { rm1[i] = __builtin_inff(); rm2[i] = __builtin_inff(); ra1[i] = 0u; }

  #pragma unroll 1
  for (int tile = 0; tile < 2; ++tile) {
    const int c0 = colBase + tile * 128;
    size_t bOff[4];
    #pragma unroll
    for (int i = 0; i < 4; ++i) bOff[i] = (size_t)(c0 + rloc[i]) * D + exel[i];

    f32x4 acc[2][8];
    #pragma unroll
    for (int m = 0; m < 2; ++m)
      #pragma unroll
      for (int n = 0; n < 8; ++n) { f32x4 z = {0.f, 0.f, 0.f, 0.f}; acc[m][n] = z; }

    #pragma unroll 1
    for (int pass = 0; pass < 3; ++pass) {
      const f16* __restrict__ A = (pass == 2) ? gLo : gHi;
      const f16* __restrict__ B = (pass == 1) ? cLo : cHi;
      #pragma unroll 1
      for (int ds = 0; ds < 8; ++ds) {
        const int d0 = ds * 64;
        __syncthreads();
        #pragma unroll
        for (int i = 0; i < 4; ++i) gl_lds16(A + aBase[i] + d0, ldsA + ldsOff[i]);
        #pragma unroll
        for (int i = 0; i < 4; ++i) gl_lds16(B + bOff[i] + d0, ldsB + ldsOff[i]);
        __syncthreads();
        #pragma unroll
        for (int ks = 0; ks < 2; ++ks) {
          const int chunk = ks * 4 + (lane >> 4);
          f16x8 af[2];
          #pragma unroll
          for (int m = 0; m < 2; ++m) {
            int r = w * 32 + m * 16 + (lane & 15);
            af[m] = *(const f16x8*)(ldsA + r * 128 + ((chunk ^ (r & 7)) * 16));
          }
          f16x8 bfr[8];
          #pragma unroll
          for (int n = 0; n < 8; ++n) {
            int r = n * 16 + (lane & 15);
            bfr[n] = *(const f16x8*)(ldsB + r * 128 + ((chunk ^ (r & 7)) * 16));
          }
          #pragma unroll
          for (int m = 0; m < 2; ++m)
            #pragma unroll
            for (int n = 0; n < 8; ++n)
              acc[m][n] = __builtin_amdgcn_mfma_f32_16x16x32_f16(af[m], bfr[n], acc[m][n], 0, 0, 0);
        }
      }
    }

    float cn[8];
    #pragma unroll
    for (int n = 0; n < 8; ++n) cn[n] = cnorm[c0 + n * 16 + (lane & 15)];
    #pragma unroll
    for (int m = 0; m < 2; ++m) {
      #pragma unroll
      for (int j = 0; j < 4; ++j) {
        float m1 = __builtin_inff(), m2 = __builtin_inff();
        unsigned a1 = 0u;
        #pragma unroll
        for (int n = 0; n < 8; ++n) {
          float v = fmaf(-2.0f, acc[m][n][j], cn[n]);
          unsigned c = (unsigned)(c0 + n * 16 + (lane & 15));
          if (v < m1) { m2 = m1; m1 = v; a1 = c; }
          else if (v < m2) { m2 = v; }
        }
        #pragma unroll
        for (int msk = 1; msk < 16; msk <<= 1) {
          float o1 = __shfl_xor(m1, msk);
          unsigned oa = (unsigned)__shfl_xor((int)a1, msk);
          float o2 = __shfl_xor(m2, msk);
          bool bet = (o1 < m1) || (o1 == m1 && oa < a1);
          float nm2 = bet ? fminf(m1, o2) : fminf(m2, o1);
          if (bet) { m1 = o1; a1 = oa; }
          m2 = nm2;
        }
        const int idx = m * 4 + j;
        bool bet = (m1 < rm1[idx]) || (m1 == rm1[idx] && a1 < ra1[idx]);
        float nm2 = bet ? fminf(rm1[idx], m2) : fminf(rm2[idx], m1);
        if (bet) { rm1[idx] = m1; ra1[idx] = a1; }
        rm2[idx] = nm2;
      }
    }
  }

  if ((lane & 15) == 0) {
    const int g = lane >> 4;
    #pragma unroll
    for (int m = 0; m < 2; ++m)
      #pragma unroll
      for (int j = 0; j < 4; ++j) {
        int a = rowBase + w * 32 + m * 16 + g * 4 + j;
        const int idx = m * 4 + j;
        float4 p;
        p.x = rm1[idx];
        p.y = __uint_as_float(ra1[idx]);
        p.z = rm2[idx];
        p.w = 0.f;
        partials2[(size_t)a * NSPAN2 + blockIdx.y] = p;
      }
  }
}

// ---- merge stage-2 spans; patch hist; still-ambiguous rows go to exact list ----
__global__ void reduce2(const float4* __restrict__ partials2, const unsigned* __restrict__ list1,
                        unsigned* __restrict__ cnts, unsigned* __restrict__ list2,
                        int* __restrict__ labels, unsigned* __restrict__ hist) {
  unsigned a = blockIdx.x * blockDim.x + threadIdx.x;
  unsigned cntA = cnts[0] < MAXA ? cnts[0] : MAXA;
  if (a >= cntA) return;
  float m1 = __builtin_inff(), m2 = __builtin_inff();
  unsigned a1 = 0u;
  #pragma unroll 4
  for (int s = 0; s < NSPAN2; ++s) {
    float4 p = partials2[(size_t)a * NSPAN2 + s];
    float o1 = p.x;
    unsigned oa = __float_as_uint(p.y);
    float o2 = p.z;
    bool bet = (o1 < m1) || (o1 == m1 && oa < a1);
    float nm2 = bet ? fminf(m1, o2) : fminf(m2, o1);
    if (bet) { m1 = o1; a1 = oa; }
    m2 = nm2;
  }
  unsigned r = list1[a];
  int old = labels[r];
  labels[r] = (int)a1;
  if (old != (int)a1) {
    atomicSub(&hist[old], 1u);
    atomicAdd(&hist[a1], 1u);
  }
  if (m2 - m1 < MARGIN2) {
    unsigned i2 = atomicAdd(&cnts[64], 1u);
    list2[i2] = r;
  }
}

// ---- stage 3: exact f64 re-scan (wave-cooperative), expected ~0-2 rows ----
__global__ __launch_bounds__(256)
void refine_scan(const float* __restrict__ target, const float* __restrict__ codebook,
                 const float* __restrict__ counts, const unsigned* __restrict__ cnts,
                 const unsigned* __restrict__ list2,
                 double* __restrict__ pv, int* __restrict__ pi, int K, int D) {
  const unsigned cnt = cnts[64];
  const unsigned nItems = cnt * 8u;
  const int w = threadIdx.x >> 6, lane = threadIdx.x & 63;
  __shared__ double sv[4];
  __shared__ int si[4];
  for (unsigned item = blockIdx.x; item < nItems; item += gridDim.x) {
    const unsigned a = item >> 3;
    const int chunk = (int)(item & 7u);
    const int r = (int)list2[a];
    const float4* t4 = (const float4*)(target + (size_t)r * D);
    float4 ta = t4[lane * 2], tb = t4[lane * 2 + 1];
    double t0 = ta.x, t1 = ta.y, t2 = ta.z, t3 = ta.w;
    double t4v = tb.x, t5 = tb.y, t6 = tb.z, t7 = tb.w;

    double bv = 1e300;
    int bc = 0;
    const int cBase = chunk * (K / 8) + w * (K / 32);
    #pragma unroll 2
    for (int i = 0; i < K / 32; ++i) {
      const int c = cBase + i;
      const float4* cb4 = (const float4*)(codebook + (size_t)c * D);
      float4 ca = cb4[lane * 2], cb = cb4[lane * 2 + 1];
      const double inv = 1.0 / (double)counts[c];
      double s = 0.0, e;
      e = t0 - (double)ca.x * inv; s = fma(e, e, s);
      e = t1 - (double)ca.y * inv; s = fma(e, e, s);
      e = t2 - (double)ca.z * inv; s = fma(e, e, s);
      e = t3 - (double)ca.w * inv; s = fma(e, e, s);
      e = t4v - (double)cb.x * inv; s = fma(e, e, s);
      e = t5 - (double)cb.y * inv; s = fma(e, e, s);
      e = t6 - (double)cb.z * inv; s = fma(e, e, s);
      e = t7 - (double)cb.w * inv; s = fma(e, e, s);
      #pragma unroll
      for (int m = 1; m < 64; m <<= 1) s += __shfl_xor(s, m);
      if (s < bv) { bv = s; bc = c; }
    }
    if (lane == 0) { sv[w] = bv; si[w] = bc; }
    __syncthreads();
    if (threadIdx.x == 0) {
      double m = sv[0];
      int bi = si[0];
      #pragma unroll
      for (int t = 1; t < 4; ++t)
        if (sv[t] < m || (sv[t] == m && si[t] < bi)) { m = sv[t]; bi = si[t]; }
      pv[(size_t)a * 8 + chunk] = m;
      pi[(size_t)a * 8 + chunk] = bi;
    }
    __syncthreads();
  }
}

__global__ void refine_merge(const double* __restrict__ pv, const int* __restrict__ pi,
                             const unsigned* __restrict__ cnts,
                             const unsigned* __restrict__ list2, int* __restrict__ labels,
                             unsigned* __restrict__ hist) {
  unsigned a = blockIdx.x * blockDim.x + threadIdx.x;
  if (a >= cnts[64]) return;
  double m = pv[(size_t)a * 8];
  int best = pi[(size_t)a * 8];
  #pragma unroll
  for (int c = 1; c < 8; ++c) {
    double v = pv[(size_t)a * 8 + c];
    int idx = pi[(size_t)a * 8 + c];
    if (v < m || (v == m && idx < best)) { m = v; best = idx; }
  }
  unsigned r = list2[a];
  int old = labels[r];
  labels[r] = best;
  if (old != best) {
    atomicSub(&hist[old], 1u);
    atomicAdd(&hist[best], 1u);
  }
}

// ---- EMA: fused counts EMA + codebook alpha-scale (one pass over hist) ----
__global__ void ema_k(const float4* __restrict__ cb4, const unsigned* __restrict__ hist,
                      const float* __restrict__ counts, float4* __restrict__ out4,
                      float* __restrict__ outCnt) {
  int k = blockIdx.x * 2 + (threadIdx.x >> 7);
  int d4 = threadIdx.x & 127;
  unsigned h = hist[k];
  float alpha = h ? DECAY : 1.0f;
  size_t i = (size_t)k * 128 + d4;
  float4 v = cb4[i];
  v.x *= alpha; v.y *= alpha; v.z *= alpha; v.w *= alpha;
  out4[i] = v;
  if (d4 == 0) outCnt[k] = alpha * counts[k] + (1.0f - alpha) * (float)h;
}

__global__ void scatter_k(const float4* __restrict__ t4, const int* __restrict__ labels,
                          float* __restrict__ outCb) {
  int n = blockIdx.x * 2 + (threadIdx.x >> 7);
  int d4 = threadIdx.x & 127;
  int lab = labels[n];
  float4 v = t4[(size_t)n * 128 + d4];
  float* dst = outCb + (size_t)lab * 512 + (d4 << 2);
  const float cc = 1.0f - DECAY;
  atomicAdd(dst + 0, cc * v.x);
  atomicAdd(dst + 1, cc * v.y);
  atomicAdd(dst + 2, cc * v.z);
  atomicAdd(dst + 3, cc * v.w);
}

// ---- fused one-hot: zeros + single 1.0 per row, float4 streaming stores ----
__global__ void onehot_k(const int* __restrict__ labels, float4* __restrict__ out, int K4) {
  const int n = blockIdx.x;
  const int lab = labels[n];
  const int lab4 = lab >> 2;
  float4* row = out + (size_t)n * K4;
  const float4 z = {0.f, 0.f, 0.f, 0.f};
  for (int c4 = threadIdx.x; c4 < K4; c4 += blockDim.x) {
    if (c4 != lab4) {
      row[c4] = z;
    } else {
      float4 v = z;
      ((float*)&v)[lab & 3] = 1.0f;
      row[c4] = v;
    }
  }
}

extern "C" void kernel_launch(void* const* d_in, const int* in_sizes, int n_in,
                              void* d_out, int out_size, void* d_ws, size_t ws_size,
                              hipStream_t stream) {
  const float* target   = (const float*)d_in[0];
  const float* codebook = (const float*)d_in[1];
  const float* counts   = (const float*)d_in[2];
  const int K = in_sizes[2];           // 8192
  const int D = in_sizes[1] / K;       // 512
  const int N = in_sizes[0] / D;       // 32768
  const int CSPAN = K / NSPAN;         // 4096

  float* outOnehot = (float*)d_out;
  float* outCb  = outOnehot + (size_t)N * K;
  float* outCnt = outCb + (size_t)K * D;

  unsigned char* p = (unsigned char*)d_ws;
  f16* tHi = (f16*)p;       p += (size_t)N * D * 2;       // 32 MB
  f16* cHi = (f16*)p;       p += (size_t)K * D * 2;       // 8 MB
  f16* cLo = (f16*)p;       p += (size_t)K * D * 2;       // 8 MB
  float* cnorm = (float*)p; p += (size_t)K * 4;
  float4* partials = (float4*)p; p += (size_t)N * NSPAN * 16;   // 1 MB
  int* labels = (int*)p;    p += (size_t)N * 4;
  unsigned* hist = (unsigned*)p;  p += (size_t)K * 4;
  unsigned* cnts = (unsigned*)p;  p += 512;                // [0]=stage1 cnt, [64]=exact cnt
  unsigned* list1 = (unsigned*)p; p += (size_t)MAXA * 4;
  unsigned* list2 = (unsigned*)p; p += (size_t)N * 4;
  f16* gHi = (f16*)p;       p += (size_t)MAXA * D * 2;     // 4 MB
  f16* gLo = (f16*)p;       p += (size_t)MAXA * D * 2;     // 4 MB
  float4* partials2 = (float4*)p; p += (size_t)MAXA * NSPAN2 * 16;  // 2 MB
  double* refpv = (double*)p;     p += (size_t)N * 8 * 8;  // 2 MB
  int* refpi = (int*)p;           p += (size_t)N * 8 * 4;  // 1 MB
  if ((size_t)(p - (unsigned char*)d_ws) > ws_size) return;  // ~63 MB

  hipLaunchKernelGGL(prep_cb, dim3(K), dim3(128), 0, stream,
                     codebook, counts, cHi, cLo, cnorm, hist, cnts, D);
  hipLaunchKernelGGL(prep_t, dim3(2048), dim3(256), 0, stream,
                     (const float4*)target, (f16x4*)tHi, (long)((size_t)N * D / 4));
  hipLaunchKernelGGL(argmin_pass, dim3(N / BM, NSPAN), dim3(256), 0, stream,
                     tHi, cHi, cnorm, partials, D, CSPAN);
  hipLaunchKernelGGL(reduce_labels, dim3((N + 255) / 256), dim3(256), 0, stream,
                     partials, labels, hist, cnts, list1, list2, N);
  hipLaunchKernelGGL(gather_k, dim3(MAXA * 128 / 256), dim3(256), 0, stream,
                     (const float4*)target, cnts, list1, (f16x4*)gHi, (f16x4*)gLo);
  hipLaunchKernelGGL(refine_mfma, dim3(MAXA / 128, NSPAN2), dim3(256), 0, stream,
                     gHi, gLo, cHi, cLo, cnorm, cnts, partials2, D);
  hipLaunchKernelGGL(reduce2, dim3((MAXA + 255) / 256), dim3(256), 0, stream,
                     partials2, list1, cnts, list2, labels, hist);
  hipLaunchKernelGGL(refine_scan, dim3(2048), dim3(256), 0, stream,
                     target, codebook, counts, cnts, list2, refpv, refpi, K, D);
  hipLaunchKernelGGL(refine_merge, dim3((N + 255) / 256), dim3(256), 0, stream,
                     refpv, refpi, cnts, list2, labels, hist);
  hipLaunchKernelGGL(ema_k, dim3(K / 2), dim3(256), 0, stream,
                     (const float4*)codebook, hist, counts, (float4*)outCb, outCnt);
  hipLaunchKernelGGL(scatter_k, dim3(N / 2), dim3(256), 0, stream,
                     (const float4*)target, labels, outCb);
  hipLaunchKernelGGL(onehot_k, dim3(N), dim3(256), 0, stream,
                     labels, (float4*)outOnehot, K / 4);
}

// Round 12
// 1110.597 us; speedup vs baseline: 1.1639x; 1.1639x over previous
//
#include <hip/hip_runtime.h>
#include <hip/hip_fp16.h>

typedef _Float16 f16;
typedef _Float16 f16x8 __attribute__((ext_vector_type(8)));
typedef _Float16 f16x4 __attribute__((ext_vector_type(4)));
typedef float    f32x4 __attribute__((ext_vector_type(4)));

#define DECAY   0.99f
#define MARGIN  0.3f     // stage-1 hh f16 pairwise error sigma ~0.026; 0.3 ~ 11 sigma (R3-validated)
#define MARGIN2 2e-3f    // stage-2 3-pass error sigma ~1.5e-4; 2e-3 ~ 13 sigma
#define MAXA    4096     // stage-2 row capacity; overflow falls through to exact f64 scan

#define BM    128   // stage-1 rows per block
#define CT    128   // codes per tile
#define BD    64    // contraction elems per stage step
#define NSPAN 2     // stage-1 K-split (R8-validated best: 512 blocks, 2/CU)
#define NSPAN2 32   // stage-2 K-split (256 cols per block)

// async global->LDS, 16B per lane, wave-uniform LDS base
__device__ __forceinline__ void gl_lds16(const void* g, void* l) {
  __builtin_amdgcn_global_load_lds(
      (const __attribute__((address_space(1))) unsigned int*)g,
      (__attribute__((address_space(3))) unsigned int*)l, 16, 0, 0);
}

// ---- prep: cb = codebook/counts, f16 hi+lo, exact f32 ||cb||^2; zero hist/counters ----
__global__ void prep_cb(const float* __restrict__ codebook, const float* __restrict__ counts,
                        f16* __restrict__ cHi, f16* __restrict__ cLo, float* __restrict__ cnorm,
                        unsigned* __restrict__ hist, unsigned* __restrict__ cnts, int D) {
  const int k = blockIdx.x;
  const int tid = threadIdx.x;  // 128 threads, D==512 -> 1 float4 each
  const float cnt = counts[k];
  float4 v = ((const float4*)(codebook + (size_t)k * D))[tid];
  float c0 = v.x / cnt, c1 = v.y / cnt, c2 = v.z / cnt, c3 = v.w / cnt;
  f16 h0 = (f16)c0, h1 = (f16)c1, h2 = (f16)c2, h3 = (f16)c3;
  f16x4 h = {h0, h1, h2, h3};
  f16x4 l = {(f16)(c0 - (float)h0), (f16)(c1 - (float)h1),
             (f16)(c2 - (float)h2), (f16)(c3 - (float)h3)};
  *(f16x4*)(cHi + (size_t)k * D + tid * 4) = h;
  *(f16x4*)(cLo + (size_t)k * D + tid * 4) = l;
  float s = c0*c0 + c1*c1 + c2*c2 + c3*c3;
  #pragma unroll
  for (int m = 1; m < 64; m <<= 1) s += __shfl_xor(s, m);
  __shared__ float red[2];
  if ((tid & 63) == 0) red[tid >> 6] = s;
  __syncthreads();
  if (tid == 0) {
    cnorm[k] = red[0] + red[1];
    hist[k] = 0u;
    if (k == 0) { cnts[0] = 0u; cnts[64] = 0u; }
  }
}

// ---- prep: target f16 hi ----
__global__ void prep_t(const float4* __restrict__ t4, f16x4* __restrict__ hi4, long total4) {
  for (long i = blockIdx.x * (long)blockDim.x + threadIdx.x; i < total4;
       i += (long)gridDim.x * blockDim.x) {
    float4 v = t4[i];
    f16x4 h = {(f16)v.x, (f16)v.y, (f16)v.z, (f16)v.w};
    hi4[i] = h;
  }
}

// ---- stage 1: lean 128x128 single-pass hh f16 MFMA, high-occupancy 2-barrier loop,
//      per-lane running top-2 across tiles, one 16-lane reduce at the end.
//      launch_bounds (256,2): do NOT cap VGPR at 128 -- (256,4) spilled (R9-R11 regression). ----
__global__ __launch_bounds__(256, 2)
void argmin_pass(const f16* __restrict__ tHi, const f16* __restrict__ cHi,
                 const float* __restrict__ cnorm, float4* __restrict__ partials,
                 int D, int CSPAN) {
  __shared__ __align__(16) unsigned char smem[2 * BM * BD * 2];  // A 16K | B 16K
  unsigned char* ldsA = smem;
  unsigned char* ldsB = smem + BM * BD * 2;

  const int tid = threadIdx.x;
  const int w = tid >> 6, lane = tid & 63;
  const int rowBase = blockIdx.x * BM;
  const int span = blockIdx.y;
  const int colBase = span * CSPAN;

  // staging map: slot s=(i*4+w)*64+lane -> row r=s>>3, 16B-chunk c=s&7; fetch chunk c^(r&7)
  // (global-source XOR swizzle; LDS linear; fragment reads apply the same XOR)
  int rloc[4], exel[4], ldsOff[4];
  #pragma unroll
  for (int i = 0; i < 4; ++i) {
    int s = (i * 4 + w) * 64 + lane;
    int r = s >> 3, c = s & 7;
    rloc[i] = r;
    exel[i] = (c ^ (r & 7)) * 8;
    ldsOff[i] = (i * 4 + w) * 1024;
  }
  size_t aBase[4];
  #pragma unroll
  for (int i = 0; i < 4; ++i) aBase[i] = (size_t)(rowBase + rloc[i]) * D + exel[i];

  // per-lane running top-2 (per m,j): candidates are this lane's 16-col slot across all tiles
  float rm1[8], rm2[8];
  unsigned ra1[8];
  #pragma unroll
  for (int i = 0; i < 8; ++i) { rm1[i] = __builtin_inff(); rm2[i] = __builtin_inff(); ra1[i] = 0u; }

  const int NT = CSPAN / CT;   // 32
  #pragma unroll 1
  for (int tile = 0; tile < NT; ++tile) {
    const int c0 = colBase + tile * CT;
    size_t bOff[4];
    #pragma unroll
    for (int i = 0; i < 4; ++i) bOff[i] = (size_t)(c0 + rloc[i]) * D + exel[i];

    f32x4 acc[2][8];
    #pragma unroll
    for (int m = 0; m < 2; ++m)
      #pragma unroll
      for (int n = 0; n < 8; ++n) { f32x4 z = {0.f, 0.f, 0.f, 0.f}; acc[m][n] = z; }

    #pragma unroll 1
    for (int ds = 0; ds < 8; ++ds) {
      const int d0 = ds * BD;
      __syncthreads();
      #pragma unroll
      for (int i = 0; i < 4; ++i) gl_lds16(tHi + aBase[i] + d0, ldsA + ldsOff[i]);
      #pragma unroll
      for (int i = 0; i < 4; ++i) gl_lds16(cHi + bOff[i] + d0, ldsB + ldsOff[i]);
      __syncthreads();
      #pragma unroll
      for (int ks = 0; ks < 2; ++ks) {
        const int chunk = ks * 4 + (lane >> 4);
        f16x8 af[2];
        #pragma unroll
        for (int m = 0; m < 2; ++m) {
          int r = w * 32 + m * 16 + (lane & 15);
          af[m] = *(const f16x8*)(ldsA + r * 128 + ((chunk ^ (r & 7)) * 16));
        }
        f16x8 bfr[8];
        #pragma unroll
        for (int n = 0; n < 8; ++n) {
          int r = n * 16 + (lane & 15);
          bfr[n] = *(const f16x8*)(ldsB + r * 128 + ((chunk ^ (r & 7)) * 16));
        }
        #pragma unroll
        for (int m = 0; m < 2; ++m)
          #pragma unroll
          for (int n = 0; n < 8; ++n)
            acc[m][n] = __builtin_amdgcn_mfma_f32_16x16x32_f16(af[m], bfr[n], acc[m][n], 0, 0, 0);
      }
    }

    // per-lane merge only (no cross-lane work inside the tile loop)
    float cn[8];
    #pragma unroll
    for (int n = 0; n < 8; ++n) cn[n] = cnorm[c0 + n * 16 + (lane & 15)];
    #pragma unroll
    for (int m = 0; m < 2; ++m) {
      #pragma unroll
      for (int j = 0; j < 4; ++j) {
        const int idx = m * 4 + j;
        float v1 = rm1[idx], v2 = rm2[idx];
        unsigned b1 = ra1[idx];
        #pragma unroll
        for (int n = 0; n < 8; ++n) {
          float v = fmaf(-2.0f, acc[m][n][j], cn[n]);
          unsigned c = (unsigned)(c0 + n * 16 + (lane & 15));
          if (v < v1) { v2 = v1; v1 = v; b1 = c; }   // strict <, ascending cols => first index
          else if (v < v2) { v2 = v; }
        }
        rm1[idx] = v1; rm2[idx] = v2; ra1[idx] = b1;
      }
    }
  }

  // final: 16-lane-group top-2 reduce, then write per-row partials
  const int g = lane >> 4;
  #pragma unroll
  for (int m = 0; m < 2; ++m) {
    #pragma unroll
    for (int j = 0; j < 4; ++j) {
      const int idx = m * 4 + j;
      float m1 = rm1[idx], m2 = rm2[idx];
      unsigned a1 = ra1[idx];
      #pragma unroll
      for (int msk = 1; msk < 16; msk <<= 1) {
        float o1 = __shfl_xor(m1, msk);
        unsigned oa = (unsigned)__shfl_xor((int)a1, msk);
        float o2 = __shfl_xor(m2, msk);
        bool bet = (o1 < m1) || (o1 == m1 && oa < a1);
        float nm2 = bet ? fminf(m1, o2) : fminf(m2, o1);
        if (bet) { m1 = o1; a1 = oa; }
        m2 = nm2;
      }
      if ((lane & 15) == 0) {
        int r = rowBase + w * 32 + m * 16 + g * 4 + j;
        float4 p;
        p.x = m1;
        p.y = __uint_as_float(a1);
        p.z = m2;
        p.w = 0.f;
        partials[(size_t)r * NSPAN + span] = p;
      }
    }
  }
}

// ---- merge stage-1 spans -> labels + inline histogram; flag ambiguous rows ----
__global__ void reduce_labels(const float4* __restrict__ partials, int* __restrict__ labels,
                              unsigned* __restrict__ hist,
                              unsigned* __restrict__ cnts, unsigned* __restrict__ list1,
                              unsigned* __restrict__ list2, int N) {
  int r = blockIdx.x * blockDim.x + threadIdx.x;
  if (r >= N) return;
  float m1 = __builtin_inff(), m2 = __builtin_inff();
  unsigned a1 = 0u;
  #pragma unroll
  for (int s = 0; s < NSPAN; ++s) {
    float4 p = partials[(size_t)r * NSPAN + s];
    float o1 = p.x;
    unsigned oa = __float_as_uint(p.y);
    float o2 = p.z;
    bool bet = (o1 < m1) || (o1 == m1 && oa < a1);
    float nm2 = bet ? fminf(m1, o2) : fminf(m2, o1);
    if (bet) { m1 = o1; a1 = oa; }
    m2 = nm2;
  }
  labels[r] = (int)a1;
  atomicAdd(&hist[a1], 1u);   // stage-1 histogram; refine stages patch deltas
  if (m2 - m1 < MARGIN) {
    unsigned idx = atomicAdd(&cnts[0], 1u);
    if (idx < MAXA) list1[idx] = (unsigned)r;
    else { unsigned i2 = atomicAdd(&cnts[64], 1u); list2[i2] = (unsigned)r; }
  }
}

// ---- gather flagged rows' targets as f16 hi/lo splits ----
__global__ void gather_k(const float4* __restrict__ t4, const unsigned* __restrict__ cnts,
                         const unsigned* __restrict__ list1, f16x4* __restrict__ gHi4,
                         f16x4* __restrict__ gLo4) {
  unsigned i = blockIdx.x * blockDim.x + threadIdx.x;  // one float4 unit
  unsigned a = i >> 7, j = i & 127;
  unsigned cntA = cnts[0] < MAXA ? cnts[0] : MAXA;
  if (a >= cntA) return;
  unsigned r = list1[a];
  float4 v = t4[(size_t)r * 128 + j];
  f16 h0 = (f16)v.x, h1 = (f16)v.y, h2 = (f16)v.z, h3 = (f16)v.w;
  f16x4 h = {h0, h1, h2, h3};
  f16x4 l = {(f16)(v.x - (float)h0), (f16)(v.y - (float)h1),
             (f16)(v.z - (float)h2), (f16)(v.w - (float)h3)};
  gHi4[(size_t)a * 128 + j] = h;
  gLo4[(size_t)a * 128 + j] = l;
}

// ---- stage 2: 3-pass (hh, h*lo, lo*h) MFMA re-score of flagged rows, full K ----
__global__ __launch_bounds__(256, 2)
void refine_mfma(const f16* __restrict__ gHi, const f16* __restrict__ gLo,
                 const f16* __restrict__ cHi, const f16* __restrict__ cLo,
                 const float* __restrict__ cnorm, const unsigned* __restrict__ cnts,
                 float4* __restrict__ partials2, int D) {
  __shared__ __align__(16) unsigned char smem[2 * 128 * 64 * 2];  // A 16K | B 16K
  unsigned char* ldsA = smem;
  unsigned char* ldsB = smem + 128 * 64 * 2;

  const unsigned cntA = cnts[0] < MAXA ? cnts[0] : MAXA;
  const int rowBase = blockIdx.x * 128;
  if ((unsigned)rowBase >= cntA) return;
  const int colBase = blockIdx.y * 256;  // CSPAN2 = 256, NT = 2

  const int tid = threadIdx.x;
  const int w = tid >> 6, lane = tid & 63;

  int rloc[4], exel[4], ldsOff[4];
  #pragma unroll
  for (int i = 0; i < 4; ++i) {
    int s = (i * 4 + w) * 64 + lane;
    int r = s >> 3, c = s & 7;
    rloc[i] = r;
    exel[i] = (c ^ (r & 7)) * 8;
    ldsOff[i] = (i * 4 + w) * 1024;
  }
  size_t aBase[4];
  #pragma unroll
  for (int i = 0; i < 4; ++i) aBase[i] = (size_t)(rowBase + rloc[i]) * D + exel[i];

  float rm1[8], rm2[8];
  unsigned ra1[8];
  #pragma unroll
  for (int i = 0; i < 8; ++i) { rm1[i] = __builtin_inff(); rm2[i] = __builtin_inff(); ra1[i] = 0u; }

  #pragma unroll 1
  for (int tile = 0; tile < 2; ++tile) {
    const int c0 = colBase + tile * 128;
    size_t bOff[4];
    #pragma unroll
    for (int i = 0; i < 4; ++i) bOff[i] = (size_t)(c0 + rloc[i]) * D + exel[i];

    f32x4 acc[2][8];
    #pragma unroll
    for (int m = 0; m < 2; ++m)
      #pragma unroll
      for (int n = 0; n < 8; ++n) { f32x4 z = {0.f, 0.f, 0.f, 0.f}; acc[m][n] = z; }

    #pragma unroll 1
    for (int pass = 0; pass < 3; ++pass) {
      const f16* __restrict__ A = (pass == 2) ? gLo : gHi;
      const f16* __restrict__ B = (pass == 1) ? cLo : cHi;
      #pragma unroll 1
      for (int ds = 0; ds < 8; ++ds) {
        const int d0 = ds * 64;
        __syncthreads();
        #pragma unroll
        for (int i = 0; i < 4; ++i) gl_lds16(A + aBase[i] + d0, ldsA + ldsOff[i]);
        #pragma unroll
        for (int i = 0; i < 4; ++i) gl_lds16(B + bOff[i] + d0, ldsB + ldsOff[i]);
        __syncthreads();
        #pragma unroll
        for (int ks = 0; ks < 2; ++ks) {
          const int chunk = ks * 4 + (lane >> 4);
          f16x8 af[2];
          #pragma unroll
          for (int m = 0; m < 2; ++m) {
            int r = w * 32 + m * 16 + (lane & 15);
            af[m] = *(const f16x8*)(ldsA + r * 128 + ((chunk ^ (r & 7)) * 16));
          }
          f16x8 bfr[8];
          #pragma unroll
          for (int n = 0; n < 8; ++n) {
            int r = n * 16 + (lane & 15);
            bfr[n] = *(const f16x8*)(ldsB + r * 128 + ((chunk ^ (r & 7)) * 16));
          }
          #pragma unroll
          for (int m = 0; m < 2; ++m)
            #pragma unroll
            for (int n = 0; n < 8; ++n)
              acc[m][n] = __builtin_amdgcn_mfma_f32_16x16x32_f16(af[m], bfr[n], acc[m][n], 0, 0, 0);
        }
      }
    }

    float cn[8];
    #pragma unroll
    for (int n = 0; n < 8; ++n) cn[n] = cnorm[c0 + n * 16 + (lane & 15)];
    #pragma unroll
    for (int m = 0; m < 2; ++m) {
      #pragma unroll
      for (int j = 0; j < 4; ++j) {
        float m1 = __builtin_inff(), m2 = __builtin_inff();
        unsigned a1 = 0u;
        #pragma unroll
        for (int n = 0; n < 8; ++n) {
          float v = fmaf(-2.0f, acc[m][n][j], cn[n]);
          unsigned c = (unsigned)(c0 + n * 16 + (lane & 15));
          if (v < m1) { m2 = m1; m1 = v; a1 = c; }
          else if (v < m2) { m2 = v; }
        }
        #pragma unroll
        for (int msk = 1; msk < 16; msk <<= 1) {
          float o1 = __shfl_xor(m1, msk);
          unsigned oa = (unsigned)__shfl_xor((int)a1, msk);
          float o2 = __shfl_xor(m2, msk);
          bool bet = (o1 < m1) || (o1 == m1 && oa < a1);
          float nm2 = bet ? fminf(m1, o2) : fminf(m2, o1);
          if (bet) { m1 = o1; a1 = oa; }
          m2 = nm2;
        }
        const int idx = m * 4 + j;
        bool bet = (m1 < rm1[idx]) || (m1 == rm1[idx] && a1 < ra1[idx]);
        float nm2 = bet ? fminf(rm1[idx], m2) : fminf(rm2[idx], m1);
        if (bet) { rm1[idx] = m1; ra1[idx] = a1; }
        rm2[idx] = nm2;
      }
    }
  }

  if ((lane & 15) == 0) {
    const int g = lane >> 4;
    #pragma unroll
    for (int m = 0; m < 2; ++m)
      #pragma unroll
      for (int j = 0; j < 4; ++j) {
        int a = rowBase + w * 32 + m * 16 + g * 4 + j;
        const int idx = m * 4 + j;
        float4 p;
        p.x = rm1[idx];
        p.y = __uint_as_float(ra1[idx]);
        p.z = rm2[idx];
        p.w = 0.f;
        partials2[(size_t)a * NSPAN2 + blockIdx.y] = p;
      }
  }
}

// ---- merge stage-2 spans; patch hist; still-ambiguous rows go to exact list ----
__global__ void reduce2(const float4* __restrict__ partials2, const unsigned* __restrict__ list1,
                        unsigned* __restrict__ cnts, unsigned* __restrict__ list2,
                        int* __restrict__ labels, unsigned* __restrict__ hist) {
  unsigned a = blockIdx.x * blockDim.x + threadIdx.x;
  unsigned cntA = cnts[0] < MAXA ? cnts[0] : MAXA;
  if (a >= cntA) return;
  float m1 = __builtin_inff(), m2 = __builtin_inff();
  unsigned a1 = 0u;
  #pragma unroll 4
  for (int s = 0; s < NSPAN2; ++s) {
    float4 p = partials2[(size_t)a * NSPAN2 + s];
    float o1 = p.x;
    unsigned oa = __float_as_uint(p.y);
    float o2 = p.z;
    bool bet = (o1 < m1) || (o1 == m1 && oa < a1);
    float nm2 = bet ? fminf(m1, o2) : fminf(m2, o1);
    if (bet) { m1 = o1; a1 = oa; }
    m2 = nm2;
  }
  unsigned r = list1[a];
  int old = labels[r];
  labels[r] = (int)a1;
  if (old != (int)a1) {
    atomicSub(&hist[old], 1u);
    atomicAdd(&hist[a1], 1u);
  }
  if (m2 - m1 < MARGIN2) {
    unsigned i2 = atomicAdd(&cnts[64], 1u);
    list2[i2] = r;
  }
}

// ---- stage 3: exact f64 re-scan (wave-cooperative), expected ~0-2 rows ----
__global__ __launch_bounds__(256)
void refine_scan(const float* __restrict__ target, const float* __restrict__ codebook,
                 const float* __restrict__ counts, const unsigned* __restrict__ cnts,
                 const unsigned* __restrict__ list2,
                 double* __restrict__ pv, int* __restrict__ pi, int K, int D) {
  const unsigned cnt = cnts[64];
  const unsigned nItems = cnt * 8u;
  const int w = threadIdx.x >> 6, lane = threadIdx.x & 63;
  __shared__ double sv[4];
  __shared__ int si[4];
  for (unsigned item = blockIdx.x; item < nItems; item += gridDim.x) {
    const unsigned a = item >> 3;
    const int chunk = (int)(item & 7u);
    const int r = (int)list2[a];
    const float4* t4 = (const float4*)(target + (size_t)r * D);
    float4 ta = t4[lane * 2], tb = t4[lane * 2 + 1];
    double t0 = ta.x, t1 = ta.y, t2 = ta.z, t3 = ta.w;
    double t4v = tb.x, t5 = tb.y, t6 = tb.z, t7 = tb.w;

    double bv = 1e300;
    int bc = 0;
    const int cBase = chunk * (K / 8) + w * (K / 32);
    #pragma unroll 2
    for (int i = 0; i < K / 32; ++i) {
      const int c = cBase + i;
      const float4* cb4 = (const float4*)(codebook + (size_t)c * D);
      float4 ca = cb4[lane * 2], cb = cb4[lane * 2 + 1];
      const double inv = 1.0 / (double)counts[c];
      double s = 0.0, e;
      e = t0 - (double)ca.x * inv; s = fma(e, e, s);
      e = t1 - (double)ca.y * inv; s = fma(e, e, s);
      e = t2 - (double)ca.z * inv; s = fma(e, e, s);
      e = t3 - (double)ca.w * inv; s = fma(e, e, s);
      e = t4v - (double)cb.x * inv; s = fma(e, e, s);
      e = t5 - (double)cb.y * inv; s = fma(e, e, s);
      e = t6 - (double)cb.z * inv; s = fma(e, e, s);
      e = t7 - (double)cb.w * inv; s = fma(e, e, s);
      #pragma unroll
      for (int m = 1; m < 64; m <<= 1) s += __shfl_xor(s, m);
      if (s < bv) { bv = s; bc = c; }
    }
    if (lane == 0) { sv[w] = bv; si[w] = bc; }
    __syncthreads();
    if (threadIdx.x == 0) {
      double m = sv[0];
      int bi = si[0];
      #pragma unroll
      for (int t = 1; t < 4; ++t)
        if (sv[t] < m || (sv[t] == m && si[t] < bi)) { m = sv[t]; bi = si[t]; }
      pv[(size_t)a * 8 + chunk] = m;
      pi[(size_t)a * 8 + chunk] = bi;
    }
    __syncthreads();
  }
}

__global__ void refine_merge(const double* __restrict__ pv, const int* __restrict__ pi,
                             const unsigned* __restrict__ cnts,
                             const unsigned* __restrict__ list2, int* __restrict__ labels,
                             unsigned* __restrict__ hist) {
  unsigned a = blockIdx.x * blockDim.x + threadIdx.x;
  if (a >= cnts[64]) return;
  double m = pv[(size_t)a * 8];
  int best = pi[(size_t)a * 8];
  #pragma unroll
  for (int c = 1; c < 8; ++c) {
    double v = pv[(size_t)a * 8 + c];
    int idx = pi[(size_t)a * 8 + c];
    if (v < m || (v == m && idx < best)) { m = v; best = idx; }
  }
  unsigned r = list2[a];
  int old = labels[r];
  labels[r] = best;
  if (old != best) {
    atomicSub(&hist[old], 1u);
    atomicAdd(&hist[best], 1u);
  }
}

// ---- EMA: fused counts EMA + codebook alpha-scale (one pass over hist) ----
__global__ void ema_k(const float4* __restrict__ cb4, const unsigned* __restrict__ hist,
                      const float* __restrict__ counts, float4* __restrict__ out4,
                      float* __restrict__ outCnt) {
  int k = blockIdx.x * 2 + (threadIdx.x >> 7);
  int d4 = threadIdx.x & 127;
  unsigned h = hist[k];
  float alpha = h ? DECAY : 1.0f;
  size_t i = (size_t)k * 128 + d4;
  float4 v = cb4[i];
  v.x *= alpha; v.y *= alpha; v.z *= alpha; v.w *= alpha;
  out4[i] = v;
  if (d4 == 0) outCnt[k] = alpha * counts[k] + (1.0f - alpha) * (float)h;
}

__global__ void scatter_k(const float4* __restrict__ t4, const int* __restrict__ labels,
                          float* __restrict__ outCb) {
  int n = blockIdx.x * 2 + (threadIdx.x >> 7);
  int d4 = threadIdx.x & 127;
  int lab = labels[n];
  float4 v = t4[(size_t)n * 128 + d4];
  float* dst = outCb + (size_t)lab * 512 + (d4 << 2);
  const float cc = 1.0f - DECAY;
  atomicAdd(dst + 0, cc * v.x);
  atomicAdd(dst + 1, cc * v.y);
  atomicAdd(dst + 2, cc * v.z);
  atomicAdd(dst + 3, cc * v.w);
}

// ---- fused one-hot: zeros + single 1.0 per row, float4 streaming stores ----
__global__ void onehot_k(const int* __restrict__ labels, float4* __restrict__ out, int K4) {
  const int n = blockIdx.x;
  const int lab = labels[n];
  const int lab4 = lab >> 2;
  float4* row = out + (size_t)n * K4;
  const float4 z = {0.f, 0.f, 0.f, 0.f};
  for (int c4 = threadIdx.x; c4 < K4; c4 += blockDim.x) {
    if (c4 != lab4) {
      row[c4] = z;
    } else {
      float4 v = z;
      ((float*)&v)[lab & 3] = 1.0f;
      row[c4] = v;
    }
  }
}

extern "C" void kernel_launch(void* const* d_in, const int* in_sizes, int n_in,
                              void* d_out, int out_size, void* d_ws, size_t ws_size,
                              hipStream_t stream) {
  const float* target   = (const float*)d_in[0];
  const float* codebook = (const float*)d_in[1];
  const float* counts   = (const float*)d_in[2];
  const int K = in_sizes[2];           // 8192
  const int D = in_sizes[1] / K;       // 512
  const int N = in_sizes[0] / D;       // 32768
  const int CSPAN = K / NSPAN;         // 4096

  float* outOnehot = (float*)d_out;
  float* outCb  = outOnehot + (size_t)N * K;
  float* outCnt = outCb + (size_t)K * D;

  unsigned char* p = (unsigned char*)d_ws;
  f16* tHi = (f16*)p;       p += (size_t)N * D * 2;       // 32 MB
  f16* cHi = (f16*)p;       p += (size_t)K * D * 2;       // 8 MB
  f16* cLo = (f16*)p;       p += (size_t)K * D * 2;       // 8 MB
  float* cnorm = (float*)p; p += (size_t)K * 4;
  float4* partials = (float4*)p; p += (size_t)N * NSPAN * 16;   // 1 MB
  int* labels = (int*)p;    p += (size_t)N * 4;
  unsigned* hist = (unsigned*)p;  p += (size_t)K * 4;
  unsigned* cnts = (unsigned*)p;  p += 512;                // [0]=stage1 cnt, [64]=exact cnt
  unsigned* list1 = (unsigned*)p; p += (size_t)MAXA * 4;
  unsigned* list2 = (unsigned*)p; p += (size_t)N * 4;
  f16* gHi = (f16*)p;       p += (size_t)MAXA * D * 2;     // 4 MB
  f16* gLo = (f16*)p;       p += (size_t)MAXA * D * 2;     // 4 MB
  float4* partials2 = (float4*)p; p += (size_t)MAXA * NSPAN2 * 16;  // 2 MB
  double* refpv = (double*)p;     p += (size_t)N * 8 * 8;  // 2 MB
  int* refpi = (int*)p;           p += (size_t)N * 8 * 4;  // 1 MB
  if ((size_t)(p - (unsigned char*)d_ws) > ws_size) return;  // ~63 MB

  hipLaunchKernelGGL(prep_cb, dim3(K), dim3(128), 0, stream,
                     codebook, counts, cHi, cLo, cnorm, hist, cnts, D);
  hipLaunchKernelGGL(prep_t, dim3(2048), dim3(256), 0, stream,
                     (const float4*)target, (f16x4*)tHi, (long)((size_t)N * D / 4));
  hipLaunchKernelGGL(argmin_pass, dim3(N / BM, NSPAN), dim3(256), 0, stream,
                     tHi, cHi, cnorm, partials, D, CSPAN);
  hipLaunchKernelGGL(reduce_labels, dim3((N + 255) / 256), dim3(256), 0, stream,
                     partials, labels, hist, cnts, list1, list2, N);
  hipLaunchKernelGGL(gather_k, dim3(MAXA * 128 / 256), dim3(256), 0, stream,
                     (const float4*)target, cnts, list1, (f16x4*)gHi, (f16x4*)gLo);
  hipLaunchKernelGGL(refine_mfma, dim3(MAXA / 128, NSPAN2), dim3(256), 0, stream,
                     gHi, gLo, cHi, cLo, cnorm, cnts, partials2, D);
  hipLaunchKernelGGL(reduce2, dim3((MAXA + 255) / 256), dim3(256), 0, stream,
                     partials2, list1, cnts, list2, labels, hist);
  hipLaunchKernelGGL(refine_scan, dim3(2048), dim3(256), 0, stream,
                     target, codebook, counts, cnts, list2, refpv, refpi, K, D);
  hipLaunchKernelGGL(refine_merge, dim3((N + 255) / 256), dim3(256), 0, stream,
                     refpv, refpi, cnts, list2, labels, hist);
  hipLaunchKernelGGL(ema_k, dim3(K / 2), dim3(256), 0, stream,
                     (const float4*)codebook, hist, counts, (float4*)outCb, outCnt);
  hipLaunchKernelGGL(scatter_k, dim3(N / 2), dim3(256), 0, stream,
                     (const float4*)target, labels, outCb);
  hipLaunchKernelGGL(onehot_k, dim3(N), dim3(256), 0, stream,
                     labels, (float4*)outOnehot, K / 4);
}